// Round 5
// baseline (968.477 us; speedup 1.0000x reference)
//
#include <hip/hip_runtime.h>
#include <math.h>

typedef _Float16 h2 __attribute__((ext_vector_type(2)));
typedef _Float16 f16x4 __attribute__((ext_vector_type(4)));
typedef float f32x4 __attribute__((ext_vector_type(4)));

#define NPOS 196
#define NH 4
#define KD 16
#define DV 64
#define DIM 256

// K=16 f16 MFMA, carried forward on gfx950.
#define MFMA16(A,B,C) __builtin_amdgcn_mfma_f32_16x16x16f16((A),(B),(C),0,0,0)

static __device__ __forceinline__ h2 pk(float a, float b) {  // RTE pack
    h2 r; r.x = (_Float16)a; r.y = (_Float16)b; return r;
}
static __device__ __forceinline__ h2 pkz(float a, float b) { // RTZ pack (hot path)
#if __has_builtin(__builtin_amdgcn_cvt_pkrtz)
    return __builtin_bit_cast(h2, __builtin_amdgcn_cvt_pkrtz(a, b));
#else
    return pk(a, b);
#endif
}
static __device__ __forceinline__ f16x4 mk4(h2 a, h2 b) {
    union { f16x4 v; h2 h[2]; } u; u.h[0] = a; u.h[1] = b; return u.v;
}

// ---------------------------------------------------------------------------
// Kernel 0: pack proj_w -> pwh A-frags [16 ot][16 kt][64 l][4 j] halves:
//             pwh value = proj_w[ot*16 + l%16][kt*16 + (l/16)*4 + j]
//           qkv_w -> qw2[(i*96+o)][c2] (half2 over c-pairs).
// ---------------------------------------------------------------------------
__global__ void cga_prep(const float* __restrict__ pw, const float* __restrict__ qw,
                         _Float16* __restrict__ pwh, h2* __restrict__ qw2) {
    const int bid = blockIdx.x, t = threadIdx.x;
    if (bid < 64) {
        const int e = bid * 256 + t;          // 0..16383 = (ot*16+kt)*64 + l
        const int l = e & 63;
        const int kt = (e >> 6) & 15;
        const int ot = e >> 10;
        const int lr = l & 15, lq = l >> 4;
        f16x4 v;
#pragma unroll
        for (int j = 0; j < 4; ++j)
            v[j] = (_Float16)pw[(ot * 16 + lr) * DIM + kt * 16 + lq * 4 + j];
        *(f16x4*)(pwh + (size_t)e * 4) = v;
    } else {
        const int idx = (bid - 64) * 256 + t;  // 0..12287 = 384*32
        const int c2 = idx & 31, oo = idx >> 5;
        qw2[idx] = pk(qw[oo * 64 + 2 * c2], qw[oo * 64 + 2 * c2 + 1]);
    }
}

// ---------------------------------------------------------------------------
// Kernel 1: fused cascaded attention, MFMA 16x16x16 f16 for QKV / QK^T / AV.
// 512 threads (8 waves) per block, one block per batch.
// 13 n-tiles of 16 (196->208 padded); wave w owns n-tiles {w, w+8}.
// Conv is split over 2 groups of 256 threads (8 channels each).
// Fragment facts (gfx950 v_mfma_f32_16x16x16_f16):
//   A[m][k]: lane holds m = l%16, k = (l/16)*4 + j
//   B[k][n]: lane holds n = l%16, k = (l/16)*4 + j
//   D[m][n]: lane holds n = l%16, m = (l/16)*4 + j
// Identities: K-proj D-frag == QK^T A-frag (K in 26 VGPRs, never LDS);
//             QK^T(S^T) D-frag == AV B-frag (P stays in registers).
// Output is stored as pre-packed proj B-frags:
//   frag[((b*16 + i*4+dt)*13 + nt)*256 + l*4 + j] = relu(O)[dt*16+lq*4+j][nt*16+lr]
// LDS map (65104 B, 2 blocks/CU -> 16 waves/CU):
//   xf [0,28288)      halves [208][68]  feat (fp16), rows 196..207 zero
//   vt [28288,55936)  halves [64][216]  V [d][m]; cols 196..207 zeroed/head
//      ql (alias)     fp32 [16][196]    pre-conv q (dead before vt written)
//   qn [55936,64256)  halves [208][20]  post-gelu q' [n][k], pad rows zero
//   bl [64256,65104)  fp32 [212]        attention bias row (shifted -4)
// ---------------------------------------------------------------------------
__global__ __launch_bounds__(512, 2) void cga_main(
    const float* __restrict__ x,      // (512,256,196)
    const h2*    __restrict__ qw2,    // (4,96,32) half2 = rows of 64 halves
    const float* __restrict__ qkv_s,  // (4,96)
    const float* __restrict__ qkv_b,  // (4,96)
    const float* __restrict__ dw_w,   // (4,16,25)
    const float* __restrict__ dw_s,   // (4,16)
    const float* __restrict__ dw_b,   // (4,16)
    const float* __restrict__ ab,     // (4,196)
    _Float16* __restrict__ frag)      // (512,16,13,256) halves, B-frag packed
{
    __shared__ __align__(16) char smem[65104];
    _Float16* xf = (_Float16*)smem;             // pitch 68 halves (136 B)
    _Float16* vt = (_Float16*)(smem + 28288);   // pitch 216 halves (432 B)
    float*    ql = (float*)(smem + 28288);      // pitch 196 f32 (alias vt)
    _Float16* qn = (_Float16*)(smem + 55936);   // pitch 20 halves (40 B)
    float*    bl = (float*)(smem + 64256);

    const int t  = threadIdx.x;
    const int l  = t & 63;
    const int w  = t >> 6;       // wave id 0..7
    const int lr = l & 15;       // lane % 16
    const int lq = l >> 4;       // lane / 16 (quarter)
    const int b  = blockIdx.x;
    const bool act = t < NPOS;          // group-0 position ownership
    const int cg  = t >> 8;             // conv channel group (0: ch0..7, 1: ch8..15)
    const int tc  = t & 255;
    const bool cact = tc < NPOS;
    const int np  = cact ? tc : (NPOS - 1);   // conv position
    const int rn  = np / 14;
    const int cn  = np - rn * 14;

    const float* xb = x + (size_t)b * (DIM * NPOS);

    // ---- init: xf <- x (head-0 feat), zero pads ---------------------------
    if (act) {
#pragma unroll
        for (int c2 = 0; c2 < 16; ++c2)
            *(h2*)(xf + t * 68 + 2 * c2) =
                pk(xb[(2 * c2) * NPOS + t], xb[(2 * c2 + 1) * NPOS + t]);
    }
    if (cg == 1 && cact) {
#pragma unroll
        for (int c2 = 16; c2 < 32; ++c2)
            *(h2*)(xf + np * 68 + 2 * c2) =
                pk(xb[(2 * c2) * NPOS + np], xb[(2 * c2 + 1) * NPOS + np]);
    }
    if (t < 204) {  // xf rows 196..207: 12 rows * 68 halves = 204 * 4 halves
        int row = 196 + t / 17, off = t - (t / 17) * 17;
        *(float2*)(xf + row * 68 + off * 4) = make_float2(0.f, 0.f);
    }
    if (t < 60) {   // qn rows 196..207: 12 rows * 20 halves = 60 * 4 halves
        int row = 196 + t / 5, off = t - (t / 5) * 5;
        *(float2*)(qn + row * 20 + off * 4) = make_float2(0.f, 0.f);
    }
    __syncthreads();

    const f32x4 fz = {0.f, 0.f, 0.f, 0.f};

#pragma unroll 1
    for (int i = 0; i < NH; ++i) {
        const _Float16* wq = (const _Float16*)qw2 + (size_t)i * (96 * 64);
        const float* sc = qkv_s + i * 96;
        const float* bi = qkv_b + i * 96;

        if (t < NPOS)      bl[t] = ab[i * NPOS + t] - 4.0f;  // softmax-invariant
        else if (t < 212)  bl[t] = 0.f;

        // ---- p1a: q projection (o 0..15) -> ql fp32 -----------------------
        {
            f16x4 aq0 = *(const f16x4*)(wq + lr * 64 +  0 + lq * 4);
            f16x4 aq1 = *(const f16x4*)(wq + lr * 64 + 16 + lq * 4);
            f16x4 aq2 = *(const f16x4*)(wq + lr * 64 + 32 + lq * 4);
            f16x4 aq3 = *(const f16x4*)(wq + lr * 64 + 48 + lq * 4);
            float s0 = sc[lq * 4 + 0], s1 = sc[lq * 4 + 1];
            float s2 = sc[lq * 4 + 2], s3 = sc[lq * 4 + 3];
            float b0 = bi[lq * 4 + 0], b1 = bi[lq * 4 + 1];
            float b2 = bi[lq * 4 + 2], b3 = bi[lq * 4 + 3];
#pragma unroll 1
            for (int nt = w; nt < 13; nt += 8) {
                const _Float16* xr = xf + (nt * 16 + lr) * 68;
                f32x4 acc = fz;
                acc = MFMA16(aq0, *(const f16x4*)(xr +  0 + lq * 4), acc);
                acc = MFMA16(aq1, *(const f16x4*)(xr + 16 + lq * 4), acc);
                acc = MFMA16(aq2, *(const f16x4*)(xr + 32 + lq * 4), acc);
                acc = MFMA16(aq3, *(const f16x4*)(xr + 48 + lq * 4), acc);
                int nn = nt * 16 + lr;
                if (nn < NPOS) {
                    ql[(lq * 4 + 0) * NPOS + nn] = fmaf(acc[0], s0, b0);
                    ql[(lq * 4 + 1) * NPOS + nn] = fmaf(acc[1], s1, b1);
                    ql[(lq * 4 + 2) * NPOS + nn] = fmaf(acc[2], s2, b2);
                    ql[(lq * 4 + 3) * NPOS + nn] = fmaf(acc[3], s3, b3);
                }
            }
        }
        __syncthreads();  // B1: ql ready

        // ---- p2: 5x5 depthwise conv + affine + gelu + residual -> qn ------
        // 8 channels per 256-thread group.
        {
            const int ch0 = 8 * cg;
            const float* dww = dw_w + i * (KD * 25);
            const float* dws = dw_s + i * KD;
            const float* dwb = dw_b + i * KD;
            float q2[8];
#pragma unroll
            for (int ch = 0; ch < 8; ++ch) {
                const int c = ch0 + ch;
                float s = 0.f;
#pragma unroll
                for (int kr = 0; kr < 5; ++kr) {
                    int rr = rn + kr - 2;
                    bool rok = (unsigned)rr < 14u;
#pragma unroll
                    for (int kc = 0; kc < 5; ++kc) {
                        int cc = cn + kc - 2;
                        bool ok = rok && ((unsigned)cc < 14u);
                        int idx = ok ? (rr * 14 + cc) : np;
                        float qv = ql[c * NPOS + idx];
                        qv = ok ? qv : 0.f;
                        s = fmaf(qv, dww[c * 25 + kr * 5 + kc], s);
                    }
                }
                float dv = fmaf(s, dws[c], dwb[c]);
                float g = 0.5f * dv * (1.f + erff(dv * 0.70710678118654752f));
                q2[ch] = g + ql[c * NPOS + np];
            }
            if (cact) {
#pragma unroll
                for (int e = 0; e < 4; ++e)
                    *(h2*)(qn + np * 20 + ch0 + 2 * e) = pk(q2[2 * e], q2[2 * e + 1]);
            }
        }
        __syncthreads();  // B2: conv done reading ql; vt may overwrite it

        // ---- p1b: K projection -> kf regs (redundant per wave);
        //           V projection -> vt [d][m] ------------------------------
        f16x4 kf[13];
        {
            f16x4 ak0 = *(const f16x4*)(wq + (16 + lr) * 64 +  0 + lq * 4);
            f16x4 ak1 = *(const f16x4*)(wq + (16 + lr) * 64 + 16 + lq * 4);
            f16x4 ak2 = *(const f16x4*)(wq + (16 + lr) * 64 + 32 + lq * 4);
            f16x4 ak3 = *(const f16x4*)(wq + (16 + lr) * 64 + 48 + lq * 4);
            float ks0 = sc[16 + lq * 4 + 0], ks1 = sc[16 + lq * 4 + 1];
            float ks2 = sc[16 + lq * 4 + 2], ks3 = sc[16 + lq * 4 + 3];
            float kb0 = bi[16 + lq * 4 + 0], kb1 = bi[16 + lq * 4 + 1];
            float kb2 = bi[16 + lq * 4 + 2], kb3 = bi[16 + lq * 4 + 3];
#pragma unroll
            for (int mt = 0; mt < 13; ++mt) {
                const _Float16* xr = xf + (mt * 16 + lr) * 68;
                f32x4 acc = fz;
                acc = MFMA16(ak0, *(const f16x4*)(xr +  0 + lq * 4), acc);
                acc = MFMA16(ak1, *(const f16x4*)(xr + 16 + lq * 4), acc);
                acc = MFMA16(ak2, *(const f16x4*)(xr + 32 + lq * 4), acc);
                acc = MFMA16(ak3, *(const f16x4*)(xr + 48 + lq * 4), acc);
                kf[mt] = mk4(pk(fmaf(acc[0], ks0, kb0), fmaf(acc[1], ks1, kb1)),
                             pk(fmaf(acc[2], ks2, kb2), fmaf(acc[3], ks3, kb3)));
            }
            // V projection: o 32..95
            f16x4 av[16];
            float vs[16], vb[16];
#pragma unroll
            for (int ot = 0; ot < 4; ++ot) {
#pragma unroll
                for (int k4 = 0; k4 < 4; ++k4)
                    av[ot * 4 + k4] = *(const f16x4*)(wq + (32 + ot * 16 + lr) * 64
                                                      + k4 * 16 + lq * 4);
#pragma unroll
                for (int j = 0; j < 4; ++j) {
                    vs[ot * 4 + j] = sc[32 + ot * 16 + lq * 4 + j];
                    vb[ot * 4 + j] = bi[32 + ot * 16 + lq * 4 + j];
                }
            }
#pragma unroll 1
            for (int nt = w; nt < 13; nt += 8) {
                const _Float16* xr = xf + (nt * 16 + lr) * 68;
                f16x4 bx0 = *(const f16x4*)(xr +  0 + lq * 4);
                f16x4 bx1 = *(const f16x4*)(xr + 16 + lq * 4);
                f16x4 bx2 = *(const f16x4*)(xr + 32 + lq * 4);
                f16x4 bx3 = *(const f16x4*)(xr + 48 + lq * 4);
                int m = nt * 16 + lr;
                bool mok = m < NPOS;
#pragma unroll
                for (int ot = 0; ot < 4; ++ot) {
                    f32x4 acc = fz;
                    acc = MFMA16(av[ot * 4 + 0], bx0, acc);
                    acc = MFMA16(av[ot * 4 + 1], bx1, acc);
                    acc = MFMA16(av[ot * 4 + 2], bx2, acc);
                    acc = MFMA16(av[ot * 4 + 3], bx3, acc);
                    if (mok) {
#pragma unroll
                        for (int j = 0; j < 4; ++j)
                            vt[(ot * 16 + lq * 4 + j) * 216 + m] =
                                (_Float16)fmaf(acc[j], vs[ot * 4 + j], vb[ot * 4 + j]);
                    }
                }
            }
            if (t < 192) {  // zero vt cols 196..207 (64 rows * 12 halves)
                int row = t / 3, off = t - (t / 3) * 3;
                *(float2*)(vt + row * 216 + 196 + off * 4) = make_float2(0.f, 0.f);
            }
        }
        __syncthreads();  // B3: qn, vt ready

        // ---- p4: S^T = K^T Q' (MFMA) -> softmax in-reg -> O = V P^T -------
        _Float16* fh = frag + ((size_t)b * 16 + i * 4) * (13 * 256);
        const float* xnp = xb + (size_t)(i + 1) * (DV * NPOS);
        const bool more = (i < NH - 1);
#pragma unroll 1
        for (int nt = w; nt < 13; nt += 8) {
            int nn = nt * 16 + lr;
            bool nok = nn < NPOS;
            int rnn = (nn * 4682) >> 16;
            int cnn = nn - rnn * 14;
            f16x4 qb = *(const f16x4*)(qn + nn * 20 + lq * 4);
            f16x4 pf[13];
            float den = 0.f;
#pragma unroll
            for (int mt = 0; mt < 13; ++mt) {
                f32x4 sv = MFMA16(kf[mt], qb, fz);
                float p0, p1, p2, p3;
                {
                    int m0 = mt * 16 + lq * 4;
                    int rm0 = (m0 * 4682) >> 16;       int cm0 = m0 - rm0 * 14;
                    int rm1 = ((m0 + 1) * 4682) >> 16; int cm1 = m0 + 1 - rm1 * 14;
                    int rm2 = ((m0 + 2) * 4682) >> 16; int cm2 = m0 + 2 - rm2 * 14;
                    int rm3 = ((m0 + 3) * 4682) >> 16; int cm3 = m0 + 3 - rm3 * 14;
                    int dr0 = rnn - rm0; dr0 = dr0 < 0 ? -dr0 : dr0;
                    int dr1 = rnn - rm1; dr1 = dr1 < 0 ? -dr1 : dr1;
                    int dr2 = rnn - rm2; dr2 = dr2 < 0 ? -dr2 : dr2;
                    int dr3 = rnn - rm3; dr3 = dr3 < 0 ? -dr3 : dr3;
                    int dc0 = cnn - cm0; dc0 = dc0 < 0 ? -dc0 : dc0;
                    int dc1 = cnn - cm1; dc1 = dc1 < 0 ? -dc1 : dc1;
                    int dc2 = cnn - cm2; dc2 = dc2 < 0 ? -dc2 : dc2;
                    int dc3 = cnn - cm3; dc3 = dc3 < 0 ? -dc3 : dc3;
                    p0 = __expf(fmaf(sv[0], 0.25f, bl[dr0 * 14 + dc0]));
                    p1 = __expf(fmaf(sv[1], 0.25f, bl[dr1 * 14 + dc1]));
                    p2 = __expf(fmaf(sv[2], 0.25f, bl[dr2 * 14 + dc2]));
                    p3 = __expf(fmaf(sv[3], 0.25f, bl[dr3 * 14 + dc3]));
                    if (m0 + 3 >= NPOS) {  // only last m-tile can clip
                        p0 = (m0 + 0 < NPOS) ? p0 : 0.f;
                        p1 = (m0 + 1 < NPOS) ? p1 : 0.f;
                        p2 = (m0 + 2 < NPOS) ? p2 : 0.f;
                        p3 = (m0 + 3 < NPOS) ? p3 : 0.f;
                    }
                }
                den += p0 + p1 + p2 + p3;
                pf[mt] = mk4(pkz(p0, p1), pkz(p2, p3));
            }
            den += __shfl_xor(den, 16, 64);
            den += __shfl_xor(den, 32, 64);
            float inv = 1.f / den;

            f32x4 o0 = fz, o1 = fz, o2 = fz, o3 = fz;
#pragma unroll
            for (int mt = 0; mt < 13; ++mt) {
                const _Float16* vr = vt + mt * 16 + lq * 4;
                o0 = MFMA16(*(const f16x4*)(vr + ( 0 + lr) * 216), pf[mt], o0);
                o1 = MFMA16(*(const f16x4*)(vr + (16 + lr) * 216), pf[mt], o1);
                o2 = MFMA16(*(const f16x4*)(vr + (32 + lr) * 216), pf[mt], o2);
                o3 = MFMA16(*(const f16x4*)(vr + (48 + lr) * 216), pf[mt], o3);
            }
            // Epilogue: store relu(O) as pre-packed proj B-frag; update xf.
            auto epi = [&](f32x4 oa, int dt) {
                f16x4 st;
                if (nok) {
                    float v0 = oa[0] * inv, v1 = oa[1] * inv;
                    float v2 = oa[2] * inv, v3 = oa[3] * inv;
                    st = mk4(pk(fmaxf(v0, 0.f), fmaxf(v1, 0.f)),
                             pk(fmaxf(v2, 0.f), fmaxf(v3, 0.f)));
                    if (more) {
                        int c0 = dt * 16 + lq * 4;
                        f16x4 fw = mk4(pk(v0 + xnp[(c0 + 0) * NPOS + nn],
                                          v1 + xnp[(c0 + 1) * NPOS + nn]),
                                       pk(v2 + xnp[(c0 + 2) * NPOS + nn],
                                          v3 + xnp[(c0 + 3) * NPOS + nn]));
                        *(f16x4*)(xf + nn * 68 + c0) = fw;
                    }
                } else {
                    st[0] = st[1] = st[2] = st[3] = (_Float16)0.f;
                }
                *(f16x4*)(fh + (dt * 13 + nt) * 256 + l * 4) = st;
            };
            epi(o0, 0); epi(o1, 1); epi(o2, 2); epi(o3, 3);
        }
        __syncthreads();  // B4: xf updated for next head
    }
}

// ---------------------------------------------------------------------------
// Kernel 2: proj GEMM via MFMA on pre-packed fragments. One block per batch,
// 512 threads (8 waves); wave w owns out-tiles {2w, 2w+1}. No LDS.
// ---------------------------------------------------------------------------
__global__ __launch_bounds__(512, 2) void cga_proj(
    const _Float16* __restrict__ frag,   // (512,16,13,256) halves, B-frag packed
    const _Float16* __restrict__ pwh,    // (16,16,256) halves, A-frag packed
    const float* __restrict__ ps, const float* __restrict__ pb,
    float* __restrict__ out)             // (512,256,196) f32
{
    const int t = threadIdx.x;
    const int l = t & 63;
    const int w = t >> 6;
    const int lr = l & 15, lq = l >> 4;
    const int b = blockIdx.x;
    const int ot0 = 2 * w;

    f16x4 a0[16], a1[16];
#pragma unroll
    for (int kt = 0; kt < 16; ++kt) {
        a0[kt] = *(const f16x4*)(pwh + (size_t)((ot0 * 16 + kt) * 64 + l) * 4);
        a1[kt] = *(const f16x4*)(pwh + (size_t)(((ot0 + 1) * 16 + kt) * 64 + l) * 4);
    }
    float s0[4], bb0[4], s1[4], bb1[4];
#pragma unroll
    for (int j = 0; j < 4; ++j) {
        s0[j]  = ps[ot0 * 16 + lq * 4 + j];
        bb0[j] = pb[ot0 * 16 + lq * 4 + j];
        s1[j]  = ps[(ot0 + 1) * 16 + lq * 4 + j];
        bb1[j] = pb[(ot0 + 1) * 16 + lq * 4 + j];
    }

    const _Float16* fb = frag + (size_t)b * (16 * 13 * 256);
    const f32x4 fz = {0.f, 0.f, 0.f, 0.f};
#pragma unroll 1
    for (int nt = 0; nt < 13; ++nt) {
        f32x4 acc0 = fz, acc1 = fz;
#pragma unroll
        for (int kt = 0; kt < 16; ++kt) {
            f16x4 bf = *(const f16x4*)(fb + (kt * 13 + nt) * 256 + l * 4);
            acc0 = MFMA16(a0[kt], bf, acc0);
            acc1 = MFMA16(a1[kt], bf, acc1);
        }
        int nn = nt * 16 + lr;
        if (nn < NPOS) {
            float* ob = out + (size_t)b * (DIM * NPOS) + nn;
#pragma unroll
            for (int j = 0; j < 4; ++j) {
                ob[(ot0 * 16 + lq * 4 + j) * NPOS] = fmaf(acc0[j], s0[j], bb0[j]);
                ob[((ot0 + 1) * 16 + lq * 4 + j) * NPOS] = fmaf(acc1[j], s1[j], bb1[j]);
            }
        }
    }
}

extern "C" void kernel_launch(void* const* d_in, const int* in_sizes, int n_in,
                              void* d_out, int out_size, void* d_ws, size_t ws_size,
                              hipStream_t stream) {
    const float* x      = (const float*)d_in[0];
    const float* qkv_w  = (const float*)d_in[1];
    const float* qkv_s  = (const float*)d_in[2];
    const float* qkv_b  = (const float*)d_in[3];
    const float* dw_w   = (const float*)d_in[4];
    const float* dw_s   = (const float*)d_in[5];
    const float* dw_b   = (const float*)d_in[6];
    const float* proj_w = (const float*)d_in[7];
    const float* proj_s = (const float*)d_in[8];
    const float* proj_b = (const float*)d_in[9];
    const float* ab     = (const float*)d_in[10];
    float* out = (float*)d_out;

    _Float16* pwh  = (_Float16*)d_ws;                    // 65536 halves = 131072 B
    h2*       qw2  = (h2*)((char*)d_ws + 131072);        // 12288 h2 = 49152 B
    _Float16* frag = (_Float16*)((char*)d_ws + 180224);  // 512*16*13*256 halves = 54.5 MB

    cga_prep<<<112, 256, 0, stream>>>(proj_w, qkv_w, pwh, qw2);
    cga_main<<<512, 512, 0, stream>>>(x, qw2, qkv_s, qkv_b,
                                      dw_w, dw_s, dw_b, ab, frag);
    cga_proj<<<512, 512, 0, stream>>>(frag, pwh, proj_s, proj_b, out);
}

// Round 6
// 621.976 us; speedup vs baseline: 1.5571x; 1.5571x over previous
//
#include <hip/hip_runtime.h>
#include <math.h>

typedef _Float16 h2 __attribute__((ext_vector_type(2)));
typedef _Float16 f16x4 __attribute__((ext_vector_type(4)));
typedef float f32x4 __attribute__((ext_vector_type(4)));

#define NPOS 196
#define NH 4
#define KD 16
#define DV 64
#define DIM 256

// K=16 f16 MFMA, carried forward on gfx950.
#define MFMA16(A,B,C) __builtin_amdgcn_mfma_f32_16x16x16f16((A),(B),(C),0,0,0)

static __device__ __forceinline__ h2 pk(float a, float b) {  // RTE pack
    h2 r; r.x = (_Float16)a; r.y = (_Float16)b; return r;
}
static __device__ __forceinline__ h2 pkz(float a, float b) { // RTZ pack (hot path)
#if __has_builtin(__builtin_amdgcn_cvt_pkrtz)
    return __builtin_bit_cast(h2, __builtin_amdgcn_cvt_pkrtz(a, b));
#else
    return pk(a, b);
#endif
}
static __device__ __forceinline__ f16x4 mk4(h2 a, h2 b) {
    union { f16x4 v; h2 h[2]; } u; u.h[0] = a; u.h[1] = b; return u.v;
}

// ---------------------------------------------------------------------------
// Kernel 0: pack proj_w -> pwh A-frags [16 ot][16 kt][64 l][4 j] halves:
//             pwh value = proj_w[ot*16 + l%16][kt*16 + (l/16)*4 + j]
//           qkv_w -> qw2[(i*96+o)][c2] (half2 over c-pairs).
// ---------------------------------------------------------------------------
__global__ void cga_prep(const float* __restrict__ pw, const float* __restrict__ qw,
                         _Float16* __restrict__ pwh, h2* __restrict__ qw2) {
    const int bid = blockIdx.x, t = threadIdx.x;
    if (bid < 64) {
        const int e = bid * 256 + t;          // 0..16383 = (ot*16+kt)*64 + l
        const int l = e & 63;
        const int kt = (e >> 6) & 15;
        const int ot = e >> 10;
        const int lr = l & 15, lq = l >> 4;
        f16x4 v;
#pragma unroll
        for (int j = 0; j < 4; ++j)
            v[j] = (_Float16)pw[(ot * 16 + lr) * DIM + kt * 16 + lq * 4 + j];
        *(f16x4*)(pwh + (size_t)e * 4) = v;
    } else {
        const int idx = (bid - 64) * 256 + t;  // 0..12287 = 384*32
        const int c2 = idx & 31, oo = idx >> 5;
        qw2[idx] = pk(qw[oo * 64 + 2 * c2], qw[oo * 64 + 2 * c2 + 1]);
    }
}

// ---------------------------------------------------------------------------
// Kernel 1: fused cascaded attention, MFMA 16x16x16 f16 for QKV / QK^T / AV.
// EXACT R3 structure (256 threads, 4 waves, proven 247us / no spill); only
// the epilogue differs: stores pre-packed proj B-frags instead of catI.
// Fragment facts (gfx950 v_mfma_f32_16x16x16_f16):
//   A[m][k]: lane holds m = l%16, k = (l/16)*4 + j
//   B[k][n]: lane holds n = l%16, k = (l/16)*4 + j
//   D[m][n]: lane holds n = l%16, m = (l/16)*4 + j
// Identities: K-proj D-frag == QK^T A-frag (K in 26 VGPRs, never LDS);
//             QK^T(S^T) D-frag == AV B-frag (P stays in registers).
// frag[((b*16 + i*4+dt)*13 + nt)*256 + l*4 + j] = relu(O)[dt*16+lq*4+j][nt*16+lr]
// (pad positions store zeros so cga_proj can MFMA over them blindly).
// LDS map (65104 B, 2 blocks/CU):
//   xf [0,28288)      halves [208][68]  feat (fp16), rows 196..207 zero
//   vt [28288,55936)  halves [64][216]  V [d][m]; cols 196..207 zeroed/head
//      ql (alias)     fp32 [16][196]    pre-conv q (dead before vt written)
//   qn [55936,64256)  halves [208][20]  post-gelu q' [n][k], pad rows zero
//   bl [64256,65104)  fp32 [212]        attention bias row (shifted -4)
// ---------------------------------------------------------------------------
__global__ __launch_bounds__(256, 2) void cga_main(
    const float* __restrict__ x,      // (512,256,196)
    const h2*    __restrict__ qw2,    // (4,96,32) half2 = rows of 64 halves
    const float* __restrict__ qkv_s,  // (4,96)
    const float* __restrict__ qkv_b,  // (4,96)
    const float* __restrict__ dw_w,   // (4,16,25)
    const float* __restrict__ dw_s,   // (4,16)
    const float* __restrict__ dw_b,   // (4,16)
    const float* __restrict__ ab,     // (4,196)
    _Float16* __restrict__ frag)      // (512,16,13,256) halves, B-frag packed
{
    __shared__ __align__(16) char smem[65104];
    _Float16* xf = (_Float16*)smem;             // pitch 68 halves (136 B)
    _Float16* vt = (_Float16*)(smem + 28288);   // pitch 216 halves (432 B)
    float*    ql = (float*)(smem + 28288);      // pitch 196 f32 (alias vt)
    _Float16* qn = (_Float16*)(smem + 55936);   // pitch 20 halves (40 B)
    float*    bl = (float*)(smem + 64256);

    const int t  = threadIdx.x;
    const int l  = t & 63;
    const int w  = t >> 6;       // wave id 0..3
    const int lr = l & 15;       // lane % 16
    const int lq = l >> 4;       // lane / 16 (quarter)
    const int b  = blockIdx.x;
    const bool act = t < NPOS;
    const int n  = act ? t : (NPOS - 1);
    const int rn = n / 14;
    const int cn = n - rn * 14;

    const float* xb = x + (size_t)b * (DIM * NPOS);

    // ---- init: xf <- x (head-0 feat), zero pads ---------------------------
    if (act) {
#pragma unroll
        for (int c2 = 0; c2 < 32; ++c2)
            *(h2*)(xf + t * 68 + 2 * c2) =
                pk(xb[(2 * c2) * NPOS + t], xb[(2 * c2 + 1) * NPOS + t]);
    }
    if (t < 204) {  // xf rows 196..207: 12 rows * 68 halves = 204 * 4 halves
        int row = 196 + t / 17, off = t - (t / 17) * 17;
        *(float2*)(xf + row * 68 + off * 4) = make_float2(0.f, 0.f);
    }
    if (t < 60) {   // qn rows 196..207: 12 rows * 20 halves = 60 * 4 halves
        int row = 196 + t / 5, off = t - (t / 5) * 5;
        *(float2*)(qn + row * 20 + off * 4) = make_float2(0.f, 0.f);
    }
    __syncthreads();

    const f32x4 fz = {0.f, 0.f, 0.f, 0.f};

#pragma unroll 1
    for (int i = 0; i < NH; ++i) {
        const _Float16* wq = (const _Float16*)qw2 + (size_t)i * (96 * 64);
        const float* sc = qkv_s + i * 96;
        const float* bi = qkv_b + i * 96;

        if (t < NPOS)      bl[t] = ab[i * NPOS + t] - 4.0f;  // softmax-invariant
        else if (t < 212)  bl[t] = 0.f;

        // ---- p1a: q projection (o 0..15) -> ql fp32 -----------------------
        {
            f16x4 aq0 = *(const f16x4*)(wq + lr * 64 +  0 + lq * 4);
            f16x4 aq1 = *(const f16x4*)(wq + lr * 64 + 16 + lq * 4);
            f16x4 aq2 = *(const f16x4*)(wq + lr * 64 + 32 + lq * 4);
            f16x4 aq3 = *(const f16x4*)(wq + lr * 64 + 48 + lq * 4);
            float s0 = sc[lq * 4 + 0], s1 = sc[lq * 4 + 1];
            float s2 = sc[lq * 4 + 2], s3 = sc[lq * 4 + 3];
            float b0 = bi[lq * 4 + 0], b1 = bi[lq * 4 + 1];
            float b2 = bi[lq * 4 + 2], b3 = bi[lq * 4 + 3];
#pragma unroll 1
            for (int nt = w; nt < 13; nt += 4) {
                const _Float16* xr = xf + (nt * 16 + lr) * 68;
                f32x4 acc = fz;
                acc = MFMA16(aq0, *(const f16x4*)(xr +  0 + lq * 4), acc);
                acc = MFMA16(aq1, *(const f16x4*)(xr + 16 + lq * 4), acc);
                acc = MFMA16(aq2, *(const f16x4*)(xr + 32 + lq * 4), acc);
                acc = MFMA16(aq3, *(const f16x4*)(xr + 48 + lq * 4), acc);
                int nn = nt * 16 + lr;
                if (nn < NPOS) {
                    ql[(lq * 4 + 0) * NPOS + nn] = fmaf(acc[0], s0, b0);
                    ql[(lq * 4 + 1) * NPOS + nn] = fmaf(acc[1], s1, b1);
                    ql[(lq * 4 + 2) * NPOS + nn] = fmaf(acc[2], s2, b2);
                    ql[(lq * 4 + 3) * NPOS + nn] = fmaf(acc[3], s3, b3);
                }
            }
        }
        __syncthreads();  // B1: ql ready

        // ---- p2: 5x5 depthwise conv + affine + exact gelu + residual -> qn
        {
            const float* dww = dw_w + i * (KD * 25);
            const float* dws = dw_s + i * KD;
            const float* dwb = dw_b + i * KD;
            float q2[KD];
#pragma unroll
            for (int ch = 0; ch < KD; ++ch) {
                float s = 0.f;
#pragma unroll
                for (int kr = 0; kr < 5; ++kr) {
                    int rr = rn + kr - 2;
                    bool rok = (unsigned)rr < 14u;
#pragma unroll
                    for (int kc = 0; kc < 5; ++kc) {
                        int cc = cn + kc - 2;
                        bool ok = rok && ((unsigned)cc < 14u);
                        int idx = ok ? (rr * 14 + cc) : n;
                        float qv = ql[ch * NPOS + idx];
                        qv = ok ? qv : 0.f;
                        s = fmaf(qv, dww[ch * 25 + kr * 5 + kc], s);
                    }
                }
                float dv = fmaf(s, dws[ch], dwb[ch]);
                float g = 0.5f * dv * (1.f + erff(dv * 0.70710678118654752f));
                q2[ch] = g + ql[ch * NPOS + n];
            }
            if (act) {
#pragma unroll
                for (int e = 0; e < 8; ++e)
                    *(h2*)(qn + n * 20 + 2 * e) = pk(q2[2 * e], q2[2 * e + 1]);
            }
        }
        __syncthreads();  // B2: conv done reading ql; vt may overwrite it

        // ---- p1b: K projection -> kf regs (redundant per wave);
        //           V projection -> vt [d][m] ------------------------------
        f16x4 kf[13];
        {
            f16x4 ak0 = *(const f16x4*)(wq + (16 + lr) * 64 +  0 + lq * 4);
            f16x4 ak1 = *(const f16x4*)(wq + (16 + lr) * 64 + 16 + lq * 4);
            f16x4 ak2 = *(const f16x4*)(wq + (16 + lr) * 64 + 32 + lq * 4);
            f16x4 ak3 = *(const f16x4*)(wq + (16 + lr) * 64 + 48 + lq * 4);
            float ks0 = sc[16 + lq * 4 + 0], ks1 = sc[16 + lq * 4 + 1];
            float ks2 = sc[16 + lq * 4 + 2], ks3 = sc[16 + lq * 4 + 3];
            float kb0 = bi[16 + lq * 4 + 0], kb1 = bi[16 + lq * 4 + 1];
            float kb2 = bi[16 + lq * 4 + 2], kb3 = bi[16 + lq * 4 + 3];
#pragma unroll
            for (int mt = 0; mt < 13; ++mt) {
                const _Float16* xr = xf + (mt * 16 + lr) * 68;
                f32x4 acc = fz;
                acc = MFMA16(ak0, *(const f16x4*)(xr +  0 + lq * 4), acc);
                acc = MFMA16(ak1, *(const f16x4*)(xr + 16 + lq * 4), acc);
                acc = MFMA16(ak2, *(const f16x4*)(xr + 32 + lq * 4), acc);
                acc = MFMA16(ak3, *(const f16x4*)(xr + 48 + lq * 4), acc);
                kf[mt] = mk4(pk(fmaf(acc[0], ks0, kb0), fmaf(acc[1], ks1, kb1)),
                             pk(fmaf(acc[2], ks2, kb2), fmaf(acc[3], ks3, kb3)));
            }
            // V projection: o 32..95
            f16x4 av[16];
            float vs[16], vb[16];
#pragma unroll
            for (int ot = 0; ot < 4; ++ot) {
#pragma unroll
                for (int k4 = 0; k4 < 4; ++k4)
                    av[ot * 4 + k4] = *(const f16x4*)(wq + (32 + ot * 16 + lr) * 64
                                                      + k4 * 16 + lq * 4);
#pragma unroll
                for (int j = 0; j < 4; ++j) {
                    vs[ot * 4 + j] = sc[32 + ot * 16 + lq * 4 + j];
                    vb[ot * 4 + j] = bi[32 + ot * 16 + lq * 4 + j];
                }
            }
#pragma unroll 1
            for (int nt = w; nt < 13; nt += 4) {
                const _Float16* xr = xf + (nt * 16 + lr) * 68;
                f16x4 bx0 = *(const f16x4*)(xr +  0 + lq * 4);
                f16x4 bx1 = *(const f16x4*)(xr + 16 + lq * 4);
                f16x4 bx2 = *(const f16x4*)(xr + 32 + lq * 4);
                f16x4 bx3 = *(const f16x4*)(xr + 48 + lq * 4);
                int m = nt * 16 + lr;
                bool mok = m < NPOS;
#pragma unroll
                for (int ot = 0; ot < 4; ++ot) {
                    f32x4 acc = fz;
                    acc = MFMA16(av[ot * 4 + 0], bx0, acc);
                    acc = MFMA16(av[ot * 4 + 1], bx1, acc);
                    acc = MFMA16(av[ot * 4 + 2], bx2, acc);
                    acc = MFMA16(av[ot * 4 + 3], bx3, acc);
                    if (mok) {
#pragma unroll
                        for (int j = 0; j < 4; ++j)
                            vt[(ot * 16 + lq * 4 + j) * 216 + m] =
                                (_Float16)fmaf(acc[j], vs[ot * 4 + j], vb[ot * 4 + j]);
                    }
                }
            }
            if (t < 192) {  // zero vt cols 196..207 (64 rows * 12 halves)
                int row = t / 3, off = t - (t / 3) * 3;
                *(float2*)(vt + row * 216 + 196 + off * 4) = make_float2(0.f, 0.f);
            }
        }
        __syncthreads();  // B3: qn, vt ready

        // ---- p4: S^T = K^T Q' (MFMA) -> softmax in-reg -> O = V P^T -------
        _Float16* fh = frag + ((size_t)b * 16 + i * 4) * (13 * 256);
        const float* xnp = xb + (size_t)(i + 1) * (DV * NPOS);
        const bool more = (i < NH - 1);
#pragma unroll 1
        for (int nt = w; nt < 13; nt += 4) {
            int nn = nt * 16 + lr;
            bool nok = nn < NPOS;
            int rnn = (nn * 4682) >> 16;
            int cnn = nn - rnn * 14;
            f16x4 qb = *(const f16x4*)(qn + nn * 20 + lq * 4);
            f16x4 pf[13];
            float den = 0.f;
#pragma unroll
            for (int mt = 0; mt < 13; ++mt) {
                f32x4 sv = MFMA16(kf[mt], qb, fz);
                float p0, p1, p2, p3;
                {
                    int m0 = mt * 16 + lq * 4;
                    int rm0 = (m0 * 4682) >> 16;       int cm0 = m0 - rm0 * 14;
                    int rm1 = ((m0 + 1) * 4682) >> 16; int cm1 = m0 + 1 - rm1 * 14;
                    int rm2 = ((m0 + 2) * 4682) >> 16; int cm2 = m0 + 2 - rm2 * 14;
                    int rm3 = ((m0 + 3) * 4682) >> 16; int cm3 = m0 + 3 - rm3 * 14;
                    int dr0 = rnn - rm0; dr0 = dr0 < 0 ? -dr0 : dr0;
                    int dr1 = rnn - rm1; dr1 = dr1 < 0 ? -dr1 : dr1;
                    int dr2 = rnn - rm2; dr2 = dr2 < 0 ? -dr2 : dr2;
                    int dr3 = rnn - rm3; dr3 = dr3 < 0 ? -dr3 : dr3;
                    int dc0 = cnn - cm0; dc0 = dc0 < 0 ? -dc0 : dc0;
                    int dc1 = cnn - cm1; dc1 = dc1 < 0 ? -dc1 : dc1;
                    int dc2 = cnn - cm2; dc2 = dc2 < 0 ? -dc2 : dc2;
                    int dc3 = cnn - cm3; dc3 = dc3 < 0 ? -dc3 : dc3;
                    p0 = __expf(fmaf(sv[0], 0.25f, bl[dr0 * 14 + dc0]));
                    p1 = __expf(fmaf(sv[1], 0.25f, bl[dr1 * 14 + dc1]));
                    p2 = __expf(fmaf(sv[2], 0.25f, bl[dr2 * 14 + dc2]));
                    p3 = __expf(fmaf(sv[3], 0.25f, bl[dr3 * 14 + dc3]));
                    if (m0 + 3 >= NPOS) {  // only last m-tile can clip
                        p0 = (m0 + 0 < NPOS) ? p0 : 0.f;
                        p1 = (m0 + 1 < NPOS) ? p1 : 0.f;
                        p2 = (m0 + 2 < NPOS) ? p2 : 0.f;
                        p3 = (m0 + 3 < NPOS) ? p3 : 0.f;
                    }
                }
                den += p0 + p1 + p2 + p3;
                pf[mt] = mk4(pkz(p0, p1), pkz(p2, p3));
            }
            den += __shfl_xor(den, 16, 64);
            den += __shfl_xor(den, 32, 64);
            float inv = 1.f / den;

            f32x4 o0 = fz, o1 = fz, o2 = fz, o3 = fz;
#pragma unroll
            for (int mt = 0; mt < 13; ++mt) {
                const _Float16* vr = vt + mt * 16 + lq * 4;
                o0 = MFMA16(*(const f16x4*)(vr + ( 0 + lr) * 216), pf[mt], o0);
                o1 = MFMA16(*(const f16x4*)(vr + (16 + lr) * 216), pf[mt], o1);
                o2 = MFMA16(*(const f16x4*)(vr + (32 + lr) * 216), pf[mt], o2);
                o3 = MFMA16(*(const f16x4*)(vr + (48 + lr) * 216), pf[mt], o3);
            }
            // Epilogue: store relu(O) as pre-packed proj B-frag; update xf.
            auto epi = [&](f32x4 oa, int dt) {
                f16x4 st;
                if (nok) {
                    float v0 = oa[0] * inv, v1 = oa[1] * inv;
                    float v2 = oa[2] * inv, v3 = oa[3] * inv;
                    st = mk4(pk(fmaxf(v0, 0.f), fmaxf(v1, 0.f)),
                             pk(fmaxf(v2, 0.f), fmaxf(v3, 0.f)));
                    if (more) {
                        int c0 = dt * 16 + lq * 4;
                        f16x4 fw = mk4(pk(v0 + xnp[(c0 + 0) * NPOS + nn],
                                          v1 + xnp[(c0 + 1) * NPOS + nn]),
                                       pk(v2 + xnp[(c0 + 2) * NPOS + nn],
                                          v3 + xnp[(c0 + 3) * NPOS + nn]));
                        *(f16x4*)(xf + nn * 68 + c0) = fw;
                    }
                } else {
                    st[0] = st[1] = st[2] = st[3] = (_Float16)0.f;
                }
                *(f16x4*)(fh + (dt * 13 + nt) * 256 + l * 4) = st;
            };
            epi(o0, 0); epi(o1, 1); epi(o2, 2); epi(o3, 3);
        }
        __syncthreads();  // B4: xf updated for next head
    }
}

// ---------------------------------------------------------------------------
// Kernel 2: proj GEMM via MFMA on pre-packed fragments, LDS-staged coalesced
// output. Block = (b, half of out channels); 256 threads (4 waves).
// Round r: wave w computes ot = half*8 + r*4 + w over all 13 n-tiles,
// stages scaled D-frags to lout[w][16][200] f32 (pitch 200 -> row+1 shifts
// bank by 8 -> the 4-row x 16-col frag scatter is conflict-free), then all
// 256 threads write 64 channel rows as contiguous float4.
// ---------------------------------------------------------------------------
__global__ __launch_bounds__(256, 2) void cga_proj(
    const _Float16* __restrict__ frag,   // (512,16,13,256) halves, B-frag packed
    const _Float16* __restrict__ pwh,    // (16,16,256) halves, A-frag packed
    const float* __restrict__ ps, const float* __restrict__ pb,
    float* __restrict__ out)             // (512,256,196) f32
{
    __shared__ __align__(16) float lout[4][16][200];  // 51200 B
    const int t = threadIdx.x;
    const int l = t & 63;
    const int w = t >> 6;
    const int lr = l & 15, lq = l >> 4;
    const int b2 = blockIdx.x;
    const int b = b2 >> 1;
    const int half = b2 & 1;

    const _Float16* fb = frag + (size_t)b * (16 * 13 * 256);
    float* ob = out + (size_t)b * (DIM * NPOS);
    const f32x4 fz = {0.f, 0.f, 0.f, 0.f};

#pragma unroll 1
    for (int r = 0; r < 2; ++r) {
        const int ot = half * 8 + r * 4 + w;
        f16x4 af[16];
#pragma unroll
        for (int kt = 0; kt < 16; ++kt)
            af[kt] = *(const f16x4*)(pwh + (size_t)((ot * 16 + kt) * 64 + l) * 4);
        float s[4], bbv[4];
#pragma unroll
        for (int j = 0; j < 4; ++j) {
            s[j]   = ps[ot * 16 + lq * 4 + j];
            bbv[j] = pb[ot * 16 + lq * 4 + j];
        }

        // 13 n-tiles, two interleaved MFMA chains for ILP.
#pragma unroll 1
        for (int nt0 = 0; nt0 < 13; nt0 += 2) {
            const bool two = (nt0 + 1 < 13);
            f32x4 acc0 = fz, acc1 = fz;
#pragma unroll
            for (int kt = 0; kt < 16; ++kt) {
                f16x4 b0 = *(const f16x4*)(fb + (kt * 13 + nt0) * 256 + l * 4);
                acc0 = MFMA16(af[kt], b0, acc0);
                if (two) {
                    f16x4 b1 = *(const f16x4*)(fb + (kt * 13 + nt0 + 1) * 256 + l * 4);
                    acc1 = MFMA16(af[kt], b1, acc1);
                }
            }
            int c0 = nt0 * 16 + lr;
#pragma unroll
            for (int j = 0; j < 4; ++j) {
                if (c0 < NPOS)
                    lout[w][lq * 4 + j][c0] = fmaf(acc0[j], s[j], bbv[j]);
                if (two && c0 + 16 < NPOS)
                    lout[w][lq * 4 + j][c0 + 16] = fmaf(acc1[j], s[j], bbv[j]);
            }
        }
        __syncthreads();  // staged rows ready

        // cooperative coalesced write: 64 rows x 49 float4
        for (int idx = t; idx < 64 * 49; idx += 256) {
            int row = idx / 49, q = idx - row * 49;
            int wv = row >> 4, c16 = row & 15;
            int ch = (half * 8 + r * 4 + wv) * 16 + c16;
            *(float4*)(ob + ch * NPOS + 4 * q) = *(const float4*)&lout[wv][c16][4 * q];
        }
        __syncthreads();  // lout consumed; next round may restage
    }
}

extern "C" void kernel_launch(void* const* d_in, const int* in_sizes, int n_in,
                              void* d_out, int out_size, void* d_ws, size_t ws_size,
                              hipStream_t stream) {
    const float* x      = (const float*)d_in[0];
    const float* qkv_w  = (const float*)d_in[1];
    const float* qkv_s  = (const float*)d_in[2];
    const float* qkv_b  = (const float*)d_in[3];
    const float* dw_w   = (const float*)d_in[4];
    const float* dw_s   = (const float*)d_in[5];
    const float* dw_b   = (const float*)d_in[6];
    const float* proj_w = (const float*)d_in[7];
    const float* proj_s = (const float*)d_in[8];
    const float* proj_b = (const float*)d_in[9];
    const float* ab     = (const float*)d_in[10];
    float* out = (float*)d_out;

    _Float16* pwh  = (_Float16*)d_ws;                    // 65536 halves = 131072 B
    h2*       qw2  = (h2*)((char*)d_ws + 131072);        // 12288 h2 = 49152 B
    _Float16* frag = (_Float16*)((char*)d_ws + 180224);  // 512*16*13*256 halves = 54.5 MB

    cga_prep<<<112, 256, 0, stream>>>(proj_w, qkv_w, pwh, qw2);
    cga_main<<<512, 256, 0, stream>>>(x, qw2, qkv_s, qkv_b,
                                      dw_w, dw_s, dw_b, ab, frag);
    cga_proj<<<512 * 2, 256, 0, stream>>>(frag, pwh, proj_s, proj_b, out);
}